// Round 3
// baseline (934.268 us; speedup 1.0000x reference)
//
#include <hip/hip_runtime.h>
#include <math.h>

#define BATCH 8
#define CCH   256
#define HH    64
#define WW    64
#define NN    4096                    // HH*WW

#define BNC   (BATCH * NN * CCH)      // 8,388,608 elems per tensor
#define WELEMS (3 * 8 * 9 * 256 * 32) // 1,769,472 fp16 weight elems per hi/lo

typedef __bf16   bf16x8 __attribute__((ext_vector_type(8)));
typedef _Float16 f16x8  __attribute__((ext_vector_type(8)));
typedef _Float16 f16x4  __attribute__((ext_vector_type(4)));
typedef float    f32x4  __attribute__((ext_vector_type(4)));

// ---------------------------------------------------------------------------
// Weights: OIHW fp32 -> fp16 hi/lo, layout [conv][cc8][tap9][co256][ci32]
// ---------------------------------------------------------------------------
__global__ void wtrans_kernel(const float* __restrict__ w1,
                              const float* __restrict__ w2,
                              const float* __restrict__ w3,
                              _Float16* __restrict__ Whi,
                              _Float16* __restrict__ Wlo) {
    int e = blockIdx.x * 256 + threadIdx.x;      // 0 .. WELEMS-1
    int t = e;
    const int ci  = t & 31;  t >>= 5;
    const int co  = t & 255; t >>= 8;
    const int tap = t % 9;   t /= 9;
    const int cc  = t & 7;   t >>= 3;
    const int conv = t;
    const float* src = (conv == 0) ? w1 : (conv == 1) ? w2 : w3;
    const float v = src[co * 2304 + (cc * 32 + ci) * 9 + tap];
    const _Float16 h = (_Float16)v;
    Whi[e] = h;
    Wlo[e] = (_Float16)(v - (float)h);
}

// ---------------------------------------------------------------------------
// X: [b][ci][h][w] fp32 -> Xhi/Xlo fp16 [b][h][w][ci]  (transpose via LDS)
// ---------------------------------------------------------------------------
__global__ __launch_bounds__(256)
void xsplit_kernel(const float* __restrict__ X,
                   _Float16* __restrict__ Xhi, _Float16* __restrict__ Xlo) {
    __shared__ float T[64][65];
    const int h = blockIdx.x, c0 = blockIdx.y * 64, bb = blockIdx.z;
    const int t = threadIdx.x;
    const int row = t >> 2, q = (t & 3) * 16;
#pragma unroll
    for (int k = 0; k < 4; ++k) {
        float4 v = *(const float4*)&X[(((size_t)bb * CCH + c0 + row) * HH + h) * WW + q + k * 4];
        *(float4*)&T[row][q + k * 4] = v;
    }
    __syncthreads();
    f16x8 h0, h1, l0, l1;
#pragma unroll
    for (int j = 0; j < 8; ++j) {
        float v = T[q + j][row];
        _Float16 hh = (_Float16)v;
        h0[j] = hh; l0[j] = (_Float16)(v - (float)hh);
    }
#pragma unroll
    for (int j = 0; j < 8; ++j) {
        float v = T[q + 8 + j][row];
        _Float16 hh = (_Float16)v;
        h1[j] = hh; l1[j] = (_Float16)(v - (float)hh);
    }
    const size_t g = (((size_t)bb * HH + h) * WW + row) * CCH + c0 + q;
    *(f16x8*)(Xhi + g) = h0;  *(f16x8*)(Xhi + g + 8) = h1;
    *(f16x8*)(Xlo + g) = l0;  *(f16x8*)(Xlo + g + 8) = l1;
}

// ---------------------------------------------------------------------------
// MFMA implicit-GEMM conv 3x3 SAME + bias, v3:
//  - X tile padded to [4][66][32] with zeroed border cols (written once) ->
//    no per-tap boundary cmp/cndmask at all.
//  - tap/j loops fully unrolled: dh/dw compile-time, W offsets compile-time
//    (noff = (next>>2)*8192 + (next&3)*512; step 35 rolls into next cc base;
//    final overrun lands in the adjacent Wlo/next-conv region - safe, unused).
//  - per-lane LDS read bases xb[dw] precomputed; every ds_read_b128 offset is
//    a compile-time immediate -> ~zero VALU on the MFMA critical path.
//  - W fragments still direct-from-global (L2-resident), depth-1 register
//    prefetch across the unrolled (tap,j) sequence.
// ---------------------------------------------------------------------------
__global__ __launch_bounds__(512, 4)
void conv_mfma_kernel(const _Float16* __restrict__ Xhi, const _Float16* __restrict__ Xlo,
                      const _Float16* __restrict__ Whi, const _Float16* __restrict__ Wlo,
                      const float* __restrict__ b1, const float* __restrict__ b2,
                      const float* __restrict__ b3,
                      __bf16* __restrict__ Qhi, __bf16* __restrict__ Qlo,
                      __bf16* __restrict__ Khi, __bf16* __restrict__ Klo,
                      float* __restrict__ Dws) {
    const int h0   = blockIdx.x * 2;
    const int bb   = blockIdx.y;
    const int conv = blockIdx.z;
    const int tid  = threadIdx.x;
    const int wave = tid >> 6;
    const int lane = tid & 63;
    const int quad = lane >> 4;
    const int l16  = lane & 15;
    const int mg   = wave >> 2;
    const int ng   = wave & 3;

    // [4 rows][66 cols][32 ch], col 0 and 65 are zero pads
    __shared__ _Float16 XsH[4 * 66 * 32];
    __shared__ _Float16 XsL[4 * 66 * 32];

    const bool threePass = (conv < 2);
    const float* bias = (conv == 0) ? b1 : (conv == 1) ? b2 : b3;

    f32x4 acc[4][4];
#pragma unroll
    for (int j = 0; j < 4; ++j) {
        const float bv = bias[ng * 64 + j * 16 + l16];
#pragma unroll
        for (int i = 0; i < 4; ++i) acc[i][j] = (f32x4){bv, bv, bv, bv};
    }

    const f16x8 zf = {0, 0, 0, 0, 0, 0, 0, 0};
    const int xrow = tid >> 7;
    const int xw   = (tid >> 1) & 63;
    const int xch  = (tid & 1) * 16;
    const int xc0  = (tid & 1) * 2;       // first 16B-chunk index (0 or 2)

    // zero the pad columns once (cols 0 and 65, all 4 rows, all 32 ch)
    if (tid < 256) {
        const int zr = tid >> 6, zc = ((tid >> 5) & 1) ? 65 : 0, zch = tid & 31;
        XsH[(zr * 66 + zc) * 32 + zch] = (_Float16)0;
        XsL[(zr * 66 + zc) * 32 + zch] = (_Float16)0;
    }

    // per-lane LDS read bases for dw = 0,1,2 (col = i*16 + l16 + dw, padded +0)
    // addr = (row*66 + col+? ) ... read col index in padded tile = i*16+l16+dw
    int xb[3];
#pragma unroll
    for (int dw = 0; dw < 3; ++dw)
        xb[dw] = mg * 2112 + (l16 + dw) * 32 + ((quad ^ ((l16 + dw) & 3)) * 8);

    // W direct-from-global: lane offset within a tap block
    const int wl = (ng * 64 + l16) * 32 + quad * 8;
    const _Float16* WhB = Whi + (size_t)conv * 589824;
    const _Float16* WlB = Wlo + (size_t)conv * 589824;

    f16x8 bhc = *(const f16x8*)(WhB + wl);
    f16x8 blc = zf;
    if (threePass) blc = *(const f16x8*)(WlB + wl);

    for (int cc = 0; cc < 8; ++cc) {
        __syncthreads();                  // previous cc's LDS reads done
        {
            const int h = h0 - 1 + xrow;
            f16x8 a0 = zf, a1 = zf, b0 = zf, b1v = zf;
            if ((unsigned)h < (unsigned)HH) {
                const size_t g = (((size_t)bb * HH + h) * WW + xw) * CCH + cc * 32 + xch;
                a0 = *(const f16x8*)(Xhi + g);  a1 = *(const f16x8*)(Xhi + g + 8);
                b0 = *(const f16x8*)(Xlo + g);  b1v = *(const f16x8*)(Xlo + g + 8);
            }
            // write col xw+1 (data cols are 1..64), swizzle units by (col&3)
            const int col = xw + 1;
            const int lbase = (xrow * 66 + col) * 32;
            const int s3 = col & 3;
            *(f16x8*)&XsH[lbase + ((xc0 ^ s3) * 8)]       = a0;
            *(f16x8*)&XsH[lbase + (((xc0 + 1) ^ s3) * 8)] = a1;
            *(f16x8*)&XsL[lbase + ((xc0 ^ s3) * 8)]       = b0;
            *(f16x8*)&XsL[lbase + (((xc0 + 1) ^ s3) * 8)] = b1v;
        }
        __syncthreads();                  // X tile visible

        const int ccW = cc * 73728;       // scalar per-cc W base offset
#pragma unroll
        for (int tap = 0; tap < 9; ++tap) {
            const int dh = tap / 3, dw = tap % 3;          // compile-time
            f16x8 ah[4], al[4];
#pragma unroll
            for (int i = 0; i < 4; ++i) {
                const int off = xb[dw] + dh * 2112 + i * 512;  // imm-folded
                ah[i] = *(const f16x8*)&XsH[off];
                if (threePass) al[i] = *(const f16x8*)&XsL[off];
            }
#pragma unroll
            for (int j = 0; j < 4; ++j) {
                const int next = tap * 4 + j + 1;              // compile-time
                const int noff = (next >> 2) * 8192 + (next & 3) * 512;
                const f16x8 bhn = *(const f16x8*)(WhB + ccW + wl + noff);
                f16x8 bln = zf;
                if (threePass) bln = *(const f16x8*)(WlB + ccW + wl + noff);
                if (threePass) {
#pragma unroll
                    for (int i = 0; i < 4; ++i) {
                        acc[i][j] = __builtin_amdgcn_mfma_f32_16x16x32_f16(ah[i], bhc, acc[i][j], 0, 0, 0);
                        acc[i][j] = __builtin_amdgcn_mfma_f32_16x16x32_f16(al[i], bhc, acc[i][j], 0, 0, 0);
                        acc[i][j] = __builtin_amdgcn_mfma_f32_16x16x32_f16(ah[i], blc, acc[i][j], 0, 0, 0);
                    }
                } else {
#pragma unroll
                    for (int i = 0; i < 4; ++i)
                        acc[i][j] = __builtin_amdgcn_mfma_f32_16x16x32_f16(ah[i], bhc, acc[i][j], 0, 0, 0);
                }
                bhc = bhn; blc = bln;
            }
        }
    }

    const size_t nb = (size_t)bb * NN + (size_t)(h0 + mg) * 64;
    if (threePass) {
        __bf16* Hi = conv ? Khi : Qhi;
        __bf16* Lo = conv ? Klo : Qlo;
#pragma unroll
        for (int i = 0; i < 4; ++i) {
            const int wx0 = i * 16 + quad * 4;
#pragma unroll
            for (int j = 0; j < 4; ++j) {
                const int co = ng * 64 + j * 16 + l16;
#pragma unroll
                for (int r = 0; r < 4; ++r) {
                    const float v = acc[i][j][r];
                    const size_t idx = (nb + wx0 + r) * CCH + co;
                    const __bf16 h = (__bf16)v;
                    Hi[idx] = h;
                    Lo[idx] = (__bf16)(v - (float)h);
                }
            }
        }
    } else {
#pragma unroll
        for (int i = 0; i < 4; ++i) {
            const int wx0 = i * 16 + quad * 4;
#pragma unroll
            for (int j = 0; j < 4; ++j) {
                const int co = ng * 64 + j * 16 + l16;
#pragma unroll
                for (int r = 0; r < 4; ++r)
                    Dws[(nb + wx0 + r) * CCH + co] = acc[i][j][r];
            }
        }
    }
}

// ---------------------------------------------------------------------------
// Transpose D (fp32 [b][n][c]) -> Vt (fp16 [b][c][n]).
// ---------------------------------------------------------------------------
__global__ __launch_bounds__(256)
void transpose_v_kernel(const float* __restrict__ D, _Float16* __restrict__ Vt) {
    __shared__ float T[64][65];
    const int n0 = blockIdx.x * 64, c0 = blockIdx.y * 64, bb = blockIdx.z;
    const int t = threadIdx.x;
    const int row = t >> 2, q = (t & 3) * 16;
#pragma unroll
    for (int k = 0; k < 4; ++k) {
        float4 v = *(const float4*)(D + ((size_t)bb * NN + n0 + row) * CCH + c0 + q + k * 4);
        *(float4*)&T[row][q + k * 4] = v;
    }
    __syncthreads();
    f16x8 o0, o1;
#pragma unroll
    for (int j = 0; j < 8; ++j) o0[j] = (_Float16)T[q + j][row];
#pragma unroll
    for (int j = 0; j < 8; ++j) o1[j] = (_Float16)T[q + 8 + j][row];
    _Float16* dst = Vt + ((size_t)bb * CCH + c0 + row) * NN + n0 + q;
    *(f16x8*)dst = o0;
    *(f16x8*)(dst + 8) = o1;
}

// ---------------------------------------------------------------------------
// MFMA flash attention v6: 512 threads / 8 waves per block, 16 q-rows per
// wave (same 128-q block, grid 256).  2 waves/SIMD so one wave's MFMA stream
// hides the other's LDS/softmax latency.  S^T formulation, 128-kv rounds,
// K-chunk/V register-prefetch pipelining, XOR-swizzled LDS.  Dynamic LDS
// 130 KB, 1 block/CU, grid 256, batch = blockIdx&7 pins batch -> XCD.
// ---------------------------------------------------------------------------
__global__ __launch_bounds__(512, 2)
void attn_mfma_kernel(const __bf16* __restrict__ Qhi, const __bf16* __restrict__ Qlo,
                      const __bf16* __restrict__ Khi, const __bf16* __restrict__ Klo,
                      const _Float16* __restrict__ Vt, const float* __restrict__ alpha_p,
                      float* __restrict__ out) {
    const int bb = blockIdx.x & 7;     // batch -> XCD
    const int qb = blockIdx.x >> 3;    // 0..31
    const int n0 = qb * 128;
    const int tid  = threadIdx.x;
    const int wave = tid >> 6;         // 0..7
    const int lane = tid & 63;
    const int quad = lane >> 4;
    const int l16  = lane & 15;
    const int xq   = l16 & 7;

    extern __shared__ __align__(16) unsigned char smem[];
    __bf16*   KsHi = (__bf16*)(smem);                 // [128][64] swizzled
    __bf16*   KsLo = (__bf16*)(smem + 16384);         // [128][64] swizzled
    _Float16* Vs   = (_Float16*)(smem + 32768);       // [256][128] swizzled
    _Float16* Pw   = (_Float16*)(smem + 98304) + wave * 16 * 136;  // [16][136]

    // Q resident in registers as B-frags: this wave's 16 q-rows
    bf16x8 qh[8], ql[8];
    {
        const size_t base = ((size_t)bb * NN + n0 + wave * 16 + l16) * CCH + quad * 8;
#pragma unroll
        for (int ks = 0; ks < 8; ++ks) {
            qh[ks] = *(const bf16x8*)(Qhi + base + ks * 32);
            ql[ks] = *(const bf16x8*)(Qlo + base + ks * 32);
        }
    }

    f32x4 Oacc[16];    // [cf]: O^T c=cf*16+quad*4+r, q=l16
#pragma unroll
    for (int cf = 0; cf < 16; ++cf) Oacc[cf] = (f32x4){0.f, 0.f, 0.f, 0.f};
    float m_i = -INFINITY, l_i = 0.f;

    // staging coords: K: 4 thr/row (128 rows), 2x16B units each per hi/lo
    const int krow = tid >> 2, kq4 = tid & 3;
    // V: 2 thr/row (256 rows), 4x16B units per group
    const int vrow = tid >> 1, vh = tid & 1;

    bf16x8 kph[2], kpl[2];     // K-chunk prefetch regs
    f16x8  vp[4];              // V half prefetch regs

    auto kload = [&](int m0_, int cc_) {
#pragma unroll
        for (int i = 0; i < 2; ++i) {
            const int u = kq4 * 2 + i;
            const size_t g = ((size_t)bb * NN + m0_ + krow) * CCH + cc_ * 64 + u * 8;
            kph[i] = *(const bf16x8*)(Khi + g);
            kpl[i] = *(const bf16x8*)(Klo + g);
        }
    };
    auto kwrite = [&]() {
#pragma unroll
        for (int i = 0; i < 2; ++i) {
            const int u = kq4 * 2 + i;
            const int lo = krow * 64 + ((u ^ (krow & 7)) * 8);
            *(bf16x8*)&KsHi[lo] = kph[i];
            *(bf16x8*)&KsLo[lo] = kpl[i];
        }
    };
    auto vload = [&](int m0_, int grp) {
#pragma unroll
        for (int i = 0; i < 4; ++i) {
            const int u = grp * 8 + vh * 4 + i;
            vp[i] = *(const f16x8*)(Vt + ((size_t)bb * CCH + vrow) * NN + m0_ + u * 8);
        }
    };
    auto vwrite = [&](int grp) {
#pragma unroll
        for (int i = 0; i < 4; ++i) {
            const int u = grp * 8 + vh * 4 + i;
            *(f16x8*)&Vs[vrow * 128 + ((u ^ (vrow & 7)) * 8)] = vp[i];
        }
    };

    f32x4 Sacc[8];
    auto schunk = [&](int cc) {
#pragma unroll
        for (int ks = 0; ks < 2; ++ks) {
            const int kq = cc * 2 + ks;
#pragma unroll
            for (int kvt = 0; kvt < 8; ++kvt) {
                const int off = (kvt * 16 + l16) * 64 + (((ks * 4 + quad) ^ xq) * 8);
                const bf16x8 kh = *(const bf16x8*)&KsHi[off];
                const bf16x8 kl = *(const bf16x8*)&KsLo[off];
                Sacc[kvt] = __builtin_amdgcn_mfma_f32_16x16x32_bf16(kh, qh[kq], Sacc[kvt], 0, 0, 0);
                Sacc[kvt] = __builtin_amdgcn_mfma_f32_16x16x32_bf16(kl, qh[kq], Sacc[kvt], 0, 0, 0);
                Sacc[kvt] = __builtin_amdgcn_mfma_f32_16x16x32_bf16(kh, ql[kq], Sacc[kvt], 0, 0, 0);
            }
        }
    };

    // prologue: stage K chunk0 of tile 0
    kload(0, 0);
    kwrite();
    __syncthreads();

    for (int t = 0; t < 32; ++t) {
        const int m0 = t * 128;
#pragma unroll
        for (int kvt = 0; kvt < 8; ++kvt) Sacc[kvt] = (f32x4){0.f, 0.f, 0.f, 0.f};

        // ---- S chunks 0..2 with chunk c+1 prefetch ----
        for (int cc = 0; cc < 3; ++cc) {
            kload(m0, cc + 1);
            schunk(cc);
            __syncthreads();          // all waves done reading chunk cc
            kwrite();
            __syncthreads();          // chunk cc+1 visible
        }

        // ---- S chunk 3; V prefetched in two halves ----
        vload(m0, 0);
        schunk(3);
        vwrite(0);                    // V region safe: last read before tile start
        vload(m0, 1);

        // ---- online softmax over 128 kv ----
        float mx = -INFINITY;
#pragma unroll
        for (int kvt = 0; kvt < 8; ++kvt)
#pragma unroll
            for (int r = 0; r < 4; ++r) mx = fmaxf(mx, Sacc[kvt][r]);
        mx = fmaxf(mx, __shfl_xor(mx, 16, 64));
        mx = fmaxf(mx, __shfl_xor(mx, 32, 64));
        const float mnew = fmaxf(m_i, mx);
        float rs = 0.f;
#pragma unroll
        for (int kvt = 0; kvt < 8; ++kvt) {
            f16x4 pw;
#pragma unroll
            for (int r = 0; r < 4; ++r) {
                const float p = __expf(Sacc[kvt][r] - mnew);
                rs += p;
                pw[r] = (_Float16)p;
            }
            *(f16x4*)&Pw[l16 * 136 + kvt * 16 + quad * 4] = pw;
        }
        rs += __shfl_xor(rs, 16, 64);
        rs += __shfl_xor(rs, 32, 64);
        const float scale = __expf(m_i - mnew);    // 0 on first tile
        l_i = l_i * scale + rs;
        m_i = mnew;
#pragma unroll
        for (int cf = 0; cf < 16; ++cf) {
            Oacc[cf][0] *= scale;
            Oacc[cf][1] *= scale;
            Oacc[cf][2] *= scale;
            Oacc[cf][3] *= scale;
        }
        vwrite(1);
        __syncthreads();              // V visible; all waves past chunk3 reads

        // ---- O^T += V^T P^T; prefetch next tile's K chunk0 ----
        kload((t == 31) ? 0 : m0 + 128, 0);
        f16x8 pf[4];
#pragma unroll
        for (int kvf = 0; kvf < 4; ++kvf)
            pf[kvf] = *(const f16x8*)&Pw[l16 * 136 + kvf * 32 + quad * 8];
#pragma unroll
        for (int cf = 0; cf < 16; ++cf) {
#pragma unroll
            for (int kvf = 0; kvf < 4; ++kvf) {
                const f16x8 vf = *(const f16x8*)&Vs[(cf * 16 + l16) * 128 + (((kvf * 4 + quad) ^ xq) * 8)];
                Oacc[cf] = __builtin_amdgcn_mfma_f32_16x16x32_f16(vf, pf[kvf], Oacc[cf], 0, 0, 0);
            }
        }
        kwrite();                     // K buffer safe: chunk3 reads ended pre-barrier
        __syncthreads();              // chunk0(t+1) visible; V reads done
    }

    // ---- epilogue: /l, *alpha, write out[b][c][n] ----
    const float alpha = *alpha_p;
    const float inv = alpha / l_i;
    const int qg = n0 + wave * 16 + l16;
#pragma unroll
    for (int cf = 0; cf < 16; ++cf) {
#pragma unroll
        for (int r = 0; r < 4; ++r) {
            const int c = cf * 16 + quad * 4 + r;
            out[((size_t)bb * CCH + c) * NN + qg] = Oacc[cf][r] * inv;
        }
    }
}

// ---------------------------------------------------------------------------
extern "C" void kernel_launch(void* const* d_in, const int* in_sizes, int n_in,
                              void* d_out, int out_size, void* d_ws, size_t ws_size,
                              hipStream_t stream) {
    const float* X  = (const float*)d_in[0];
    const float* w1 = (const float*)d_in[1];
    const float* b1 = (const float*)d_in[2];
    const float* w2 = (const float*)d_in[3];
    const float* b2 = (const float*)d_in[4];
    const float* w3 = (const float*)d_in[5];
    const float* b3 = (const float*)d_in[6];
    const float* alpha = (const float*)d_in[7];
    float* out = (float*)d_out;

    float*    Dws = (float*)d_ws;
    __bf16*   Qhi = (__bf16*)(Dws + (size_t)BNC);
    __bf16*   Qlo = Qhi + (size_t)BNC;
    __bf16*   Khi = Qlo + (size_t)BNC;
    __bf16*   Klo = Khi + (size_t)BNC;
    _Float16* Vt  = (_Float16*)(Klo + (size_t)BNC);
    _Float16* Xhi = Vt + (size_t)BNC;
    _Float16* Xlo = Xhi + (size_t)BNC;
    _Float16* Whi = Xlo + (size_t)BNC;
    _Float16* Wlo = Whi + (size_t)WELEMS;

    wtrans_kernel<<<dim3(WELEMS / 256), 256, 0, stream>>>(w1, w2, w3, Whi, Wlo);

    xsplit_kernel<<<dim3(HH, CCH / 64, BATCH), 256, 0, stream>>>(X, Xhi, Xlo);

    conv_mfma_kernel<<<dim3(HH / 2, BATCH, 3), 512, 0, stream>>>(
        Xhi, Xlo, Whi, Wlo, b1, b2, b3, Qhi, Qlo, Khi, Klo, Dws);

    transpose_v_kernel<<<dim3(NN / 64, CCH / 64, BATCH), 256, 0, stream>>>(Dws, Vt);

    // dynamic LDS: K chunk hi/lo 32 KB + V 64 KB + P 34 KB = 133120 B
    attn_mfma_kernel<<<dim3(256), 512, 133120, stream>>>(
        Qhi, Qlo, Khi, Klo, Vt, alpha, out);
}

// Round 4
// 702.265 us; speedup vs baseline: 1.3304x; 1.3304x over previous
//
#include <hip/hip_runtime.h>
#include <math.h>

#define BATCH 8
#define CCH   256
#define HH    64
#define WW    64
#define NN    4096                    // HH*WW

#define BNC   (BATCH * NN * CCH)      // 8,388,608 elems per tensor
#define WELEMS (3 * 8 * 9 * 256 * 32) // 1,769,472 fp16 weight elems per hi/lo

typedef __bf16   bf16x8 __attribute__((ext_vector_type(8)));
typedef _Float16 f16x8  __attribute__((ext_vector_type(8)));
typedef _Float16 f16x4  __attribute__((ext_vector_type(4)));
typedef float    f32x4  __attribute__((ext_vector_type(4)));

// ---------------------------------------------------------------------------
// Weights: OIHW fp32 -> fp16 hi/lo, layout [conv][cc8][tap9][co256][ci32]
// ---------------------------------------------------------------------------
__global__ void wtrans_kernel(const float* __restrict__ w1,
                              const float* __restrict__ w2,
                              const float* __restrict__ w3,
                              _Float16* __restrict__ Whi,
                              _Float16* __restrict__ Wlo) {
    int e = blockIdx.x * 256 + threadIdx.x;      // 0 .. WELEMS-1
    int t = e;
    const int ci  = t & 31;  t >>= 5;
    const int co  = t & 255; t >>= 8;
    const int tap = t % 9;   t /= 9;
    const int cc  = t & 7;   t >>= 3;
    const int conv = t;
    const float* src = (conv == 0) ? w1 : (conv == 1) ? w2 : w3;
    const float v = src[co * 2304 + (cc * 32 + ci) * 9 + tap];
    const _Float16 h = (_Float16)v;
    Whi[e] = h;
    Wlo[e] = (_Float16)(v - (float)h);
}

// ---------------------------------------------------------------------------
// X: [b][ci][h][w] fp32 -> Xhi/Xlo fp16 [b][h][w][ci]  (transpose via LDS)
// ---------------------------------------------------------------------------
__global__ __launch_bounds__(256)
void xsplit_kernel(const float* __restrict__ X,
                   _Float16* __restrict__ Xhi, _Float16* __restrict__ Xlo) {
    __shared__ float T[64][65];
    const int h = blockIdx.x, c0 = blockIdx.y * 64, bb = blockIdx.z;
    const int t = threadIdx.x;
    const int row = t >> 2, q = (t & 3) * 16;
#pragma unroll
    for (int k = 0; k < 4; ++k) {
        float4 v = *(const float4*)&X[(((size_t)bb * CCH + c0 + row) * HH + h) * WW + q + k * 4];
        *(float4*)&T[row][q + k * 4] = v;
    }
    __syncthreads();
    f16x8 h0, h1, l0, l1;
#pragma unroll
    for (int j = 0; j < 8; ++j) {
        float v = T[q + j][row];
        _Float16 hh = (_Float16)v;
        h0[j] = hh; l0[j] = (_Float16)(v - (float)hh);
    }
#pragma unroll
    for (int j = 0; j < 8; ++j) {
        float v = T[q + 8 + j][row];
        _Float16 hh = (_Float16)v;
        h1[j] = hh; l1[j] = (_Float16)(v - (float)hh);
    }
    const size_t g = (((size_t)bb * HH + h) * WW + row) * CCH + c0 + q;
    *(f16x8*)(Xhi + g) = h0;  *(f16x8*)(Xhi + g + 8) = h1;
    *(f16x8*)(Xlo + g) = l0;  *(f16x8*)(Xlo + g + 8) = l1;
}

// ---------------------------------------------------------------------------
// MFMA implicit-GEMM conv 3x3 SAME + bias, v4:
//  v3 body (padded X tile, compile-time W/X offsets, ~8% VALUBusy) but with
//  __launch_bounds__(512, 2): v3's (512,4) capped unified regs at 128/wave
//  while the unrolled body needs ~134 (64 AGPR acc + ~70 VGPR) -> the
//  overflow spilled to scratch (WRITE_SIZE 237MB -> 1.37GB, +350MB FETCH,
//  all pipes stalled).  256-reg budget eliminates spill; occupancy 2
//  waves/SIMD (1 block/CU) is enough to co-schedule MFMA + memory streams.
// ---------------------------------------------------------------------------
__global__ __launch_bounds__(512, 2)
void conv_mfma_kernel(const _Float16* __restrict__ Xhi, const _Float16* __restrict__ Xlo,
                      const _Float16* __restrict__ Whi, const _Float16* __restrict__ Wlo,
                      const float* __restrict__ b1, const float* __restrict__ b2,
                      const float* __restrict__ b3,
                      __bf16* __restrict__ Qhi, __bf16* __restrict__ Qlo,
                      __bf16* __restrict__ Khi, __bf16* __restrict__ Klo,
                      float* __restrict__ Dws) {
    const int h0   = blockIdx.x * 2;
    const int bb   = blockIdx.y;
    const int conv = blockIdx.z;
    const int tid  = threadIdx.x;
    const int wave = tid >> 6;
    const int lane = tid & 63;
    const int quad = lane >> 4;
    const int l16  = lane & 15;
    const int mg   = wave >> 2;
    const int ng   = wave & 3;

    // [4 rows][66 cols][32 ch], col 0 and 65 are zero pads
    __shared__ _Float16 XsH[4 * 66 * 32];
    __shared__ _Float16 XsL[4 * 66 * 32];

    const bool threePass = (conv < 2);
    const float* bias = (conv == 0) ? b1 : (conv == 1) ? b2 : b3;

    f32x4 acc[4][4];
#pragma unroll
    for (int j = 0; j < 4; ++j) {
        const float bv = bias[ng * 64 + j * 16 + l16];
#pragma unroll
        for (int i = 0; i < 4; ++i) acc[i][j] = (f32x4){bv, bv, bv, bv};
    }

    const f16x8 zf = {0, 0, 0, 0, 0, 0, 0, 0};
    const int xrow = tid >> 7;
    const int xw   = (tid >> 1) & 63;
    const int xch  = (tid & 1) * 16;
    const int xc0  = (tid & 1) * 2;       // first 16B-chunk index (0 or 2)

    // zero the pad columns once (cols 0 and 65, all 4 rows, all 32 ch)
    if (tid < 256) {
        const int zr = tid >> 6, zc = ((tid >> 5) & 1) ? 65 : 0, zch = tid & 31;
        XsH[(zr * 66 + zc) * 32 + zch] = (_Float16)0;
        XsL[(zr * 66 + zc) * 32 + zch] = (_Float16)0;
    }

    // per-lane LDS read bases for dw = 0,1,2 (col = i*16 + l16 + dw, padded +0)
    int xb[3];
#pragma unroll
    for (int dw = 0; dw < 3; ++dw)
        xb[dw] = mg * 2112 + (l16 + dw) * 32 + ((quad ^ ((l16 + dw) & 3)) * 8);

    // W direct-from-global: lane offset within a tap block
    const int wl = (ng * 64 + l16) * 32 + quad * 8;
    const _Float16* WhB = Whi + (size_t)conv * 589824;
    const _Float16* WlB = Wlo + (size_t)conv * 589824;

    f16x8 bhc = *(const f16x8*)(WhB + wl);
    f16x8 blc = zf;
    if (threePass) blc = *(const f16x8*)(WlB + wl);

    for (int cc = 0; cc < 8; ++cc) {
        __syncthreads();                  // previous cc's LDS reads done
        {
            const int h = h0 - 1 + xrow;
            f16x8 a0 = zf, a1 = zf, b0 = zf, b1v = zf;
            if ((unsigned)h < (unsigned)HH) {
                const size_t g = (((size_t)bb * HH + h) * WW + xw) * CCH + cc * 32 + xch;
                a0 = *(const f16x8*)(Xhi + g);  a1 = *(const f16x8*)(Xhi + g + 8);
                b0 = *(const f16x8*)(Xlo + g);  b1v = *(const f16x8*)(Xlo + g + 8);
            }
            // write col xw+1 (data cols are 1..64), swizzle units by (col&3)
            const int col = xw + 1;
            const int lbase = (xrow * 66 + col) * 32;
            const int s3 = col & 3;
            *(f16x8*)&XsH[lbase + ((xc0 ^ s3) * 8)]       = a0;
            *(f16x8*)&XsH[lbase + (((xc0 + 1) ^ s3) * 8)] = a1;
            *(f16x8*)&XsL[lbase + ((xc0 ^ s3) * 8)]       = b0;
            *(f16x8*)&XsL[lbase + (((xc0 + 1) ^ s3) * 8)] = b1v;
        }
        __syncthreads();                  // X tile visible

        const int ccW = cc * 73728;       // scalar per-cc W base offset
#pragma unroll
        for (int tap = 0; tap < 9; ++tap) {
            const int dh = tap / 3, dw = tap % 3;          // compile-time
            f16x8 ah[4], al[4];
#pragma unroll
            for (int i = 0; i < 4; ++i) {
                const int off = xb[dw] + dh * 2112 + i * 512;  // imm-folded
                ah[i] = *(const f16x8*)&XsH[off];
                if (threePass) al[i] = *(const f16x8*)&XsL[off];
            }
#pragma unroll
            for (int j = 0; j < 4; ++j) {
                const int next = tap * 4 + j + 1;              // compile-time
                const int noff = (next >> 2) * 8192 + (next & 3) * 512;
                const f16x8 bhn = *(const f16x8*)(WhB + ccW + wl + noff);
                f16x8 bln = zf;
                if (threePass) bln = *(const f16x8*)(WlB + ccW + wl + noff);
                if (threePass) {
#pragma unroll
                    for (int i = 0; i < 4; ++i) {
                        acc[i][j] = __builtin_amdgcn_mfma_f32_16x16x32_f16(ah[i], bhc, acc[i][j], 0, 0, 0);
                        acc[i][j] = __builtin_amdgcn_mfma_f32_16x16x32_f16(al[i], bhc, acc[i][j], 0, 0, 0);
                        acc[i][j] = __builtin_amdgcn_mfma_f32_16x16x32_f16(ah[i], blc, acc[i][j], 0, 0, 0);
                    }
                } else {
#pragma unroll
                    for (int i = 0; i < 4; ++i)
                        acc[i][j] = __builtin_amdgcn_mfma_f32_16x16x32_f16(ah[i], bhc, acc[i][j], 0, 0, 0);
                }
                bhc = bhn; blc = bln;
            }
        }
    }

    const size_t nb = (size_t)bb * NN + (size_t)(h0 + mg) * 64;
    if (threePass) {
        __bf16* Hi = conv ? Khi : Qhi;
        __bf16* Lo = conv ? Klo : Qlo;
#pragma unroll
        for (int i = 0; i < 4; ++i) {
            const int wx0 = i * 16 + quad * 4;
#pragma unroll
            for (int j = 0; j < 4; ++j) {
                const int co = ng * 64 + j * 16 + l16;
#pragma unroll
                for (int r = 0; r < 4; ++r) {
                    const float v = acc[i][j][r];
                    const size_t idx = (nb + wx0 + r) * CCH + co;
                    const __bf16 h = (__bf16)v;
                    Hi[idx] = h;
                    Lo[idx] = (__bf16)(v - (float)h);
                }
            }
        }
    } else {
#pragma unroll
        for (int i = 0; i < 4; ++i) {
            const int wx0 = i * 16 + quad * 4;
#pragma unroll
            for (int j = 0; j < 4; ++j) {
                const int co = ng * 64 + j * 16 + l16;
#pragma unroll
                for (int r = 0; r < 4; ++r)
                    Dws[(nb + wx0 + r) * CCH + co] = acc[i][j][r];
            }
        }
    }
}

// ---------------------------------------------------------------------------
// Transpose D (fp32 [b][n][c]) -> Vt (fp16 [b][c][n]).
// ---------------------------------------------------------------------------
__global__ __launch_bounds__(256)
void transpose_v_kernel(const float* __restrict__ D, _Float16* __restrict__ Vt) {
    __shared__ float T[64][65];
    const int n0 = blockIdx.x * 64, c0 = blockIdx.y * 64, bb = blockIdx.z;
    const int t = threadIdx.x;
    const int row = t >> 2, q = (t & 3) * 16;
#pragma unroll
    for (int k = 0; k < 4; ++k) {
        float4 v = *(const float4*)(D + ((size_t)bb * NN + n0 + row) * CCH + c0 + q + k * 4);
        *(float4*)&T[row][q + k * 4] = v;
    }
    __syncthreads();
    f16x8 o0, o1;
#pragma unroll
    for (int j = 0; j < 8; ++j) o0[j] = (_Float16)T[q + j][row];
#pragma unroll
    for (int j = 0; j < 8; ++j) o1[j] = (_Float16)T[q + 8 + j][row];
    _Float16* dst = Vt + ((size_t)bb * CCH + c0 + row) * NN + n0 + q;
    *(f16x8*)dst = o0;
    *(f16x8*)(dst + 8) = o1;
}

// ---------------------------------------------------------------------------
// MFMA flash attention v6: 512 threads / 8 waves per block, 16 q-rows per
// wave (same 128-q block, grid 256).  2 waves/SIMD so one wave's MFMA stream
// hides the other's LDS/softmax latency.  S^T formulation, 128-kv rounds,
// K-chunk/V register-prefetch pipelining, XOR-swizzled LDS.  Dynamic LDS
// 130 KB, 1 block/CU, grid 256, batch = blockIdx&7 pins batch -> XCD.
// ---------------------------------------------------------------------------
__global__ __launch_bounds__(512, 2)
void attn_mfma_kernel(const __bf16* __restrict__ Qhi, const __bf16* __restrict__ Qlo,
                      const __bf16* __restrict__ Khi, const __bf16* __restrict__ Klo,
                      const _Float16* __restrict__ Vt, const float* __restrict__ alpha_p,
                      float* __restrict__ out) {
    const int bb = blockIdx.x & 7;     // batch -> XCD
    const int qb = blockIdx.x >> 3;    // 0..31
    const int n0 = qb * 128;
    const int tid  = threadIdx.x;
    const int wave = tid >> 6;         // 0..7
    const int lane = tid & 63;
    const int quad = lane >> 4;
    const int l16  = lane & 15;
    const int xq   = l16 & 7;

    extern __shared__ __align__(16) unsigned char smem[];
    __bf16*   KsHi = (__bf16*)(smem);                 // [128][64] swizzled
    __bf16*   KsLo = (__bf16*)(smem + 16384);         // [128][64] swizzled
    _Float16* Vs   = (_Float16*)(smem + 32768);       // [256][128] swizzled
    _Float16* Pw   = (_Float16*)(smem + 98304) + wave * 16 * 136;  // [16][136]

    // Q resident in registers as B-frags: this wave's 16 q-rows
    bf16x8 qh[8], ql[8];
    {
        const size_t base = ((size_t)bb * NN + n0 + wave * 16 + l16) * CCH + quad * 8;
#pragma unroll
        for (int ks = 0; ks < 8; ++ks) {
            qh[ks] = *(const bf16x8*)(Qhi + base + ks * 32);
            ql[ks] = *(const bf16x8*)(Qlo + base + ks * 32);
        }
    }

    f32x4 Oacc[16];    // [cf]: O^T c=cf*16+quad*4+r, q=l16
#pragma unroll
    for (int cf = 0; cf < 16; ++cf) Oacc[cf] = (f32x4){0.f, 0.f, 0.f, 0.f};
    float m_i = -INFINITY, l_i = 0.f;

    // staging coords: K: 4 thr/row (128 rows), 2x16B units each per hi/lo
    const int krow = tid >> 2, kq4 = tid & 3;
    // V: 2 thr/row (256 rows), 4x16B units per group
    const int vrow = tid >> 1, vh = tid & 1;

    bf16x8 kph[2], kpl[2];     // K-chunk prefetch regs
    f16x8  vp[4];              // V half prefetch regs

    auto kload = [&](int m0_, int cc_) {
#pragma unroll
        for (int i = 0; i < 2; ++i) {
            const int u = kq4 * 2 + i;
            const size_t g = ((size_t)bb * NN + m0_ + krow) * CCH + cc_ * 64 + u * 8;
            kph[i] = *(const bf16x8*)(Khi + g);
            kpl[i] = *(const bf16x8*)(Klo + g);
        }
    };
    auto kwrite = [&]() {
#pragma unroll
        for (int i = 0; i < 2; ++i) {
            const int u = kq4 * 2 + i;
            const int lo = krow * 64 + ((u ^ (krow & 7)) * 8);
            *(bf16x8*)&KsHi[lo] = kph[i];
            *(bf16x8*)&KsLo[lo] = kpl[i];
        }
    };
    auto vload = [&](int m0_, int grp) {
#pragma unroll
        for (int i = 0; i < 4; ++i) {
            const int u = grp * 8 + vh * 4 + i;
            vp[i] = *(const f16x8*)(Vt + ((size_t)bb * CCH + vrow) * NN + m0_ + u * 8);
        }
    };
    auto vwrite = [&](int grp) {
#pragma unroll
        for (int i = 0; i < 4; ++i) {
            const int u = grp * 8 + vh * 4 + i;
            *(f16x8*)&Vs[vrow * 128 + ((u ^ (vrow & 7)) * 8)] = vp[i];
        }
    };

    f32x4 Sacc[8];
    auto schunk = [&](int cc) {
#pragma unroll
        for (int ks = 0; ks < 2; ++ks) {
            const int kq = cc * 2 + ks;
#pragma unroll
            for (int kvt = 0; kvt < 8; ++kvt) {
                const int off = (kvt * 16 + l16) * 64 + (((ks * 4 + quad) ^ xq) * 8);
                const bf16x8 kh = *(const bf16x8*)&KsHi[off];
                const bf16x8 kl = *(const bf16x8*)&KsLo[off];
                Sacc[kvt] = __builtin_amdgcn_mfma_f32_16x16x32_bf16(kh, qh[kq], Sacc[kvt], 0, 0, 0);
                Sacc[kvt] = __builtin_amdgcn_mfma_f32_16x16x32_bf16(kl, qh[kq], Sacc[kvt], 0, 0, 0);
                Sacc[kvt] = __builtin_amdgcn_mfma_f32_16x16x32_bf16(kh, ql[kq], Sacc[kvt], 0, 0, 0);
            }
        }
    };

    // prologue: stage K chunk0 of tile 0
    kload(0, 0);
    kwrite();
    __syncthreads();

    for (int t = 0; t < 32; ++t) {
        const int m0 = t * 128;
#pragma unroll
        for (int kvt = 0; kvt < 8; ++kvt) Sacc[kvt] = (f32x4){0.f, 0.f, 0.f, 0.f};

        // ---- S chunks 0..2 with chunk c+1 prefetch ----
        for (int cc = 0; cc < 3; ++cc) {
            kload(m0, cc + 1);
            schunk(cc);
            __syncthreads();          // all waves done reading chunk cc
            kwrite();
            __syncthreads();          // chunk cc+1 visible
        }

        // ---- S chunk 3; V prefetched in two halves ----
        vload(m0, 0);
        schunk(3);
        vwrite(0);                    // V region safe: last read before tile start
        vload(m0, 1);

        // ---- online softmax over 128 kv ----
        float mx = -INFINITY;
#pragma unroll
        for (int kvt = 0; kvt < 8; ++kvt)
#pragma unroll
            for (int r = 0; r < 4; ++r) mx = fmaxf(mx, Sacc[kvt][r]);
        mx = fmaxf(mx, __shfl_xor(mx, 16, 64));
        mx = fmaxf(mx, __shfl_xor(mx, 32, 64));
        const float mnew = fmaxf(m_i, mx);
        float rs = 0.f;
#pragma unroll
        for (int kvt = 0; kvt < 8; ++kvt) {
            f16x4 pw;
#pragma unroll
            for (int r = 0; r < 4; ++r) {
                const float p = __expf(Sacc[kvt][r] - mnew);
                rs += p;
                pw[r] = (_Float16)p;
            }
            *(f16x4*)&Pw[l16 * 136 + kvt * 16 + quad * 4] = pw;
        }
        rs += __shfl_xor(rs, 16, 64);
        rs += __shfl_xor(rs, 32, 64);
        const float scale = __expf(m_i - mnew);    // 0 on first tile
        l_i = l_i * scale + rs;
        m_i = mnew;
#pragma unroll
        for (int cf = 0; cf < 16; ++cf) {
            Oacc[cf][0] *= scale;
            Oacc[cf][1] *= scale;
            Oacc[cf][2] *= scale;
            Oacc[cf][3] *= scale;
        }
        vwrite(1);
        __syncthreads();              // V visible; all waves past chunk3 reads

        // ---- O^T += V^T P^T; prefetch next tile's K chunk0 ----
        kload((t == 31) ? 0 : m0 + 128, 0);
        f16x8 pf[4];
#pragma unroll
        for (int kvf = 0; kvf < 4; ++kvf)
            pf[kvf] = *(const f16x8*)&Pw[l16 * 136 + kvf * 32 + quad * 8];
#pragma unroll
        for (int cf = 0; cf < 16; ++cf) {
#pragma unroll
            for (int kvf = 0; kvf < 4; ++kvf) {
                const f16x8 vf = *(const f16x8*)&Vs[(cf * 16 + l16) * 128 + (((kvf * 4 + quad) ^ xq) * 8)];
                Oacc[cf] = __builtin_amdgcn_mfma_f32_16x16x32_f16(vf, pf[kvf], Oacc[cf], 0, 0, 0);
            }
        }
        kwrite();                     // K buffer safe: chunk3 reads ended pre-barrier
        __syncthreads();              // chunk0(t+1) visible; V reads done
    }

    // ---- epilogue: /l, *alpha, write out[b][c][n] ----
    const float alpha = *alpha_p;
    const float inv = alpha / l_i;
    const int qg = n0 + wave * 16 + l16;
#pragma unroll
    for (int cf = 0; cf < 16; ++cf) {
#pragma unroll
        for (int r = 0; r < 4; ++r) {
            const int c = cf * 16 + quad * 4 + r;
            out[((size_t)bb * CCH + c) * NN + qg] = Oacc[cf][r] * inv;
        }
    }
}

// ---------------------------------------------------------------------------
extern "C" void kernel_launch(void* const* d_in, const int* in_sizes, int n_in,
                              void* d_out, int out_size, void* d_ws, size_t ws_size,
                              hipStream_t stream) {
    const float* X  = (const float*)d_in[0];
    const float* w1 = (const float*)d_in[1];
    const float* b1 = (const float*)d_in[2];
    const float* w2 = (const float*)d_in[3];
    const float* b2 = (const float*)d_in[4];
    const float* w3 = (const float*)d_in[5];
    const float* b3 = (const float*)d_in[6];
    const float* alpha = (const float*)d_in[7];
    float* out = (float*)d_out;

    float*    Dws = (float*)d_ws;
    __bf16*   Qhi = (__bf16*)(Dws + (size_t)BNC);
    __bf16*   Qlo = Qhi + (size_t)BNC;
    __bf16*   Khi = Qlo + (size_t)BNC;
    __bf16*   Klo = Khi + (size_t)BNC;
    _Float16* Vt  = (_Float16*)(Klo + (size_t)BNC);
    _Float16* Xhi = Vt + (size_t)BNC;
    _Float16* Xlo = Xhi + (size_t)BNC;
    _Float16* Whi = Xlo + (size_t)BNC;
    _Float16* Wlo = Whi + (size_t)WELEMS;

    wtrans_kernel<<<dim3(WELEMS / 256), 256, 0, stream>>>(w1, w2, w3, Whi, Wlo);

    xsplit_kernel<<<dim3(HH, CCH / 64, BATCH), 256, 0, stream>>>(X, Xhi, Xlo);

    conv_mfma_kernel<<<dim3(HH / 2, BATCH, 3), 512, 0, stream>>>(
        Xhi, Xlo, Whi, Wlo, b1, b2, b3, Qhi, Qlo, Khi, Klo, Dws);

    transpose_v_kernel<<<dim3(NN / 64, CCH / 64, BATCH), 256, 0, stream>>>(Dws, Vt);

    // dynamic LDS: K chunk hi/lo 32 KB + V 64 KB + P 34 KB = 133120 B
    attn_mfma_kernel<<<dim3(256), 512, 133120, stream>>>(
        Qhi, Qlo, Khi, Klo, Vt, alpha, out);
}

// Round 5
// 601.516 us; speedup vs baseline: 1.5532x; 1.1675x over previous
//
#include <hip/hip_runtime.h>
#include <math.h>

#define BATCH 8
#define CCH   256
#define HH    64
#define WW    64
#define NN    4096                    // HH*WW

#define BNC   (BATCH * NN * CCH)      // 8,388,608 elems per tensor
#define WELEMS (3 * 8 * 9 * 256 * 32) // 1,769,472 fp16 weight elems per hi/lo

typedef __bf16   bf16x8 __attribute__((ext_vector_type(8)));
typedef _Float16 f16x8  __attribute__((ext_vector_type(8)));
typedef _Float16 f16x4  __attribute__((ext_vector_type(4)));
typedef float    f32x4  __attribute__((ext_vector_type(4)));

// ---------------------------------------------------------------------------
// Weights: OIHW fp32 -> fp16 hi/lo, layout [conv][cc8][tap9][co256][ci32]
// ---------------------------------------------------------------------------
__global__ void wtrans_kernel(const float* __restrict__ w1,
                              const float* __restrict__ w2,
                              const float* __restrict__ w3,
                              _Float16* __restrict__ Whi,
                              _Float16* __restrict__ Wlo) {
    int e = blockIdx.x * 256 + threadIdx.x;      // 0 .. WELEMS-1
    int t = e;
    const int ci  = t & 31;  t >>= 5;
    const int co  = t & 255; t >>= 8;
    const int tap = t % 9;   t /= 9;
    const int cc  = t & 7;   t >>= 3;
    const int conv = t;
    const float* src = (conv == 0) ? w1 : (conv == 1) ? w2 : w3;
    const float v = src[co * 2304 + (cc * 32 + ci) * 9 + tap];
    const _Float16 h = (_Float16)v;
    Whi[e] = h;
    Wlo[e] = (_Float16)(v - (float)h);
}

// ---------------------------------------------------------------------------
// X: [b][ci][h][w] fp32 -> Xhi/Xlo fp16 [b][h][w][ci]  (transpose via LDS)
// ---------------------------------------------------------------------------
__global__ __launch_bounds__(256)
void xsplit_kernel(const float* __restrict__ X,
                   _Float16* __restrict__ Xhi, _Float16* __restrict__ Xlo) {
    __shared__ float T[64][65];
    const int h = blockIdx.x, c0 = blockIdx.y * 64, bb = blockIdx.z;
    const int t = threadIdx.x;
    const int row = t >> 2, q = (t & 3) * 16;
#pragma unroll
    for (int k = 0; k < 4; ++k) {
        float4 v = *(const float4*)&X[(((size_t)bb * CCH + c0 + row) * HH + h) * WW + q + k * 4];
        *(float4*)&T[row][q + k * 4] = v;
    }
    __syncthreads();
    f16x8 h0, h1, l0, l1;
#pragma unroll
    for (int j = 0; j < 8; ++j) {
        float v = T[q + j][row];
        _Float16 hh = (_Float16)v;
        h0[j] = hh; l0[j] = (_Float16)(v - (float)hh);
    }
#pragma unroll
    for (int j = 0; j < 8; ++j) {
        float v = T[q + 8 + j][row];
        _Float16 hh = (_Float16)v;
        h1[j] = hh; l1[j] = (_Float16)(v - (float)hh);
    }
    const size_t g = (((size_t)bb * HH + h) * WW + row) * CCH + c0 + q;
    *(f16x8*)(Xhi + g) = h0;  *(f16x8*)(Xhi + g + 8) = h1;
    *(f16x8*)(Xlo + g) = l0;  *(f16x8*)(Xlo + g + 8) = l1;
}

// ---------------------------------------------------------------------------
// MFMA implicit-GEMM conv 3x3 SAME + bias, v5:
//  - v4 body (padded X tile, compile-time offsets) but acc shrunk 4x4 -> 4x2
//    per wave (32 AGPR): live regs ~116 < 128, so __launch_bounds__(512,4)
//    holds WITHOUT spill (v3 failed at 152 regs).  4 waves/SIMD + 2
//    blocks/CU hide ds_read latency, W-L2 prefetch latency and staging
//    barriers.
//  - Block = 1 h-row x 64 w x 256 co; 8 waves, wave = 32-co group.
//    Grid (64, 8, 3).  X tile = 3 rows [3][66][32] hi/lo = 25 KB -> 2
//    blocks/CU.  X fetch x1.5 vs v4 (HBM 8 -> ~11%, acceptable).
//  - W duplication per CU unchanged (1 wave/slice/block x 2 blocks).
// ---------------------------------------------------------------------------
__global__ __launch_bounds__(512, 4)
void conv_mfma_kernel(const _Float16* __restrict__ Xhi, const _Float16* __restrict__ Xlo,
                      const _Float16* __restrict__ Whi, const _Float16* __restrict__ Wlo,
                      const float* __restrict__ b1, const float* __restrict__ b2,
                      const float* __restrict__ b3,
                      __bf16* __restrict__ Qhi, __bf16* __restrict__ Qlo,
                      __bf16* __restrict__ Khi, __bf16* __restrict__ Klo,
                      float* __restrict__ Dws) {
    const int h    = blockIdx.x;          // output h row
    const int bb   = blockIdx.y;
    const int conv = blockIdx.z;
    const int tid  = threadIdx.x;
    const int wave = tid >> 6;            // 0..7 = ng (32-co group)
    const int lane = tid & 63;
    const int quad = lane >> 4;
    const int l16  = lane & 15;

    // [3 rows][66 cols][32 ch], col 0 and 65 are zero pads
    __shared__ _Float16 XsH[3 * 66 * 32];
    __shared__ _Float16 XsL[3 * 66 * 32];

    const bool threePass = (conv < 2);
    const float* bias = (conv == 0) ? b1 : (conv == 1) ? b2 : b3;

    f32x4 acc[4][2];
#pragma unroll
    for (int j = 0; j < 2; ++j) {
        const float bv = bias[wave * 32 + j * 16 + l16];
#pragma unroll
        for (int i = 0; i < 4; ++i) acc[i][j] = (f32x4){bv, bv, bv, bv};
    }

    const f16x8 zf = {0, 0, 0, 0, 0, 0, 0, 0};
    const int xrow = tid >> 7;            // 0..3 (row 3 idle for staging)
    const int xw   = (tid >> 1) & 63;
    const int xch  = (tid & 1) * 16;
    const int xc0  = (tid & 1) * 2;       // first 16B-chunk index (0 or 2)

    // zero the pad columns once (cols 0 and 65, rows 0..2, all 32 ch)
    if (tid < 192) {
        const int zr = tid >> 6, zc = ((tid >> 5) & 1) ? 65 : 0, zch = tid & 31;
        XsH[(zr * 66 + zc) * 32 + zch] = (_Float16)0;
        XsL[(zr * 66 + zc) * 32 + zch] = (_Float16)0;
    }

    // per-lane LDS read bases for dw = 0,1,2 (col = i*16 + l16 + dw)
    int xb[3];
#pragma unroll
    for (int dw = 0; dw < 3; ++dw)
        xb[dw] = (l16 + dw) * 32 + ((quad ^ ((l16 + dw) & 3)) * 8);

    // W direct-from-global: lane offset within a tap block.
    // step s = tap*2 + j: offset = (s>>1)*8192 + (s&1)*512 + wlane
    const int wlane = wave * 1024 + l16 * 32 + quad * 8;
    const _Float16* WhB = Whi + (size_t)conv * 589824;
    const _Float16* WlB = Wlo + (size_t)conv * 589824;

    f16x8 bhc = *(const f16x8*)(WhB + wlane);
    f16x8 blc = zf;
    if (threePass) blc = *(const f16x8*)(WlB + wlane);

    for (int cc = 0; cc < 8; ++cc) {
        __syncthreads();                  // previous cc's LDS reads done
        if (xrow < 3) {
            const int hh = h - 1 + xrow;
            f16x8 a0 = zf, a1 = zf, b0 = zf, b1v = zf;
            if ((unsigned)hh < (unsigned)HH) {
                const size_t g = (((size_t)bb * HH + hh) * WW + xw) * CCH + cc * 32 + xch;
                a0 = *(const f16x8*)(Xhi + g);  a1 = *(const f16x8*)(Xhi + g + 8);
                if (threePass) { b0 = *(const f16x8*)(Xlo + g);  b1v = *(const f16x8*)(Xlo + g + 8); }
            }
            // write col xw+1 (data cols are 1..64), swizzle units by (col&3)
            const int col = xw + 1;
            const int lbase = (xrow * 66 + col) * 32;
            const int s3 = col & 3;
            *(f16x8*)&XsH[lbase + ((xc0 ^ s3) * 8)]       = a0;
            *(f16x8*)&XsH[lbase + (((xc0 + 1) ^ s3) * 8)] = a1;
            if (threePass) {
                *(f16x8*)&XsL[lbase + ((xc0 ^ s3) * 8)]       = b0;
                *(f16x8*)&XsL[lbase + (((xc0 + 1) ^ s3) * 8)] = b1v;
            }
        }
        __syncthreads();                  // X tile visible

        const int ccW = cc * 73728;       // scalar per-cc W base offset
#pragma unroll
        for (int tap = 0; tap < 9; ++tap) {
            const int dh = tap / 3, dw = tap % 3;          // compile-time
            f16x8 ah[4], al[4];
#pragma unroll
            for (int i = 0; i < 4; ++i) {
                const int off = xb[dw] + dh * 2112 + i * 512;  // imm-folded
                ah[i] = *(const f16x8*)&XsH[off];
                if (threePass) al[i] = *(const f16x8*)&XsL[off];
            }
#pragma unroll
            for (int j = 0; j < 2; ++j) {
                const int next = tap * 2 + j + 1;              // compile-time
                const int noff = (next == 18) ? 73728
                               : (next >> 1) * 8192 + (next & 1) * 512;
                const f16x8 bhn = *(const f16x8*)(WhB + ccW + wlane + noff);
                f16x8 bln = zf;
                if (threePass) bln = *(const f16x8*)(WlB + ccW + wlane + noff);
                if (threePass) {
#pragma unroll
                    for (int i = 0; i < 4; ++i) {
                        acc[i][j] = __builtin_amdgcn_mfma_f32_16x16x32_f16(ah[i], bhc, acc[i][j], 0, 0, 0);
                        acc[i][j] = __builtin_amdgcn_mfma_f32_16x16x32_f16(al[i], bhc, acc[i][j], 0, 0, 0);
                        acc[i][j] = __builtin_amdgcn_mfma_f32_16x16x32_f16(ah[i], blc, acc[i][j], 0, 0, 0);
                    }
                } else {
#pragma unroll
                    for (int i = 0; i < 4; ++i)
                        acc[i][j] = __builtin_amdgcn_mfma_f32_16x16x32_f16(ah[i], bhc, acc[i][j], 0, 0, 0);
                }
                bhc = bhn; blc = bln;
            }
        }
    }

    const size_t nb = (size_t)bb * NN + (size_t)h * 64;
    if (threePass) {
        __bf16* Hi = conv ? Khi : Qhi;
        __bf16* Lo = conv ? Klo : Qlo;
#pragma unroll
        for (int i = 0; i < 4; ++i) {
            const int wx0 = i * 16 + quad * 4;
#pragma unroll
            for (int j = 0; j < 2; ++j) {
                const int co = wave * 32 + j * 16 + l16;
#pragma unroll
                for (int r = 0; r < 4; ++r) {
                    const float v = acc[i][j][r];
                    const size_t idx = (nb + wx0 + r) * CCH + co;
                    const __bf16 hq = (__bf16)v;
                    Hi[idx] = hq;
                    Lo[idx] = (__bf16)(v - (float)hq);
                }
            }
        }
    } else {
#pragma unroll
        for (int i = 0; i < 4; ++i) {
            const int wx0 = i * 16 + quad * 4;
#pragma unroll
            for (int j = 0; j < 2; ++j) {
                const int co = wave * 32 + j * 16 + l16;
#pragma unroll
                for (int r = 0; r < 4; ++r)
                    Dws[(nb + wx0 + r) * CCH + co] = acc[i][j][r];
            }
        }
    }
}

// ---------------------------------------------------------------------------
// Transpose D (fp32 [b][n][c]) -> Vt (fp16 [b][c][n]).
// ---------------------------------------------------------------------------
__global__ __launch_bounds__(256)
void transpose_v_kernel(const float* __restrict__ D, _Float16* __restrict__ Vt) {
    __shared__ float T[64][65];
    const int n0 = blockIdx.x * 64, c0 = blockIdx.y * 64, bb = blockIdx.z;
    const int t = threadIdx.x;
    const int row = t >> 2, q = (t & 3) * 16;
#pragma unroll
    for (int k = 0; k < 4; ++k) {
        float4 v = *(const float4*)(D + ((size_t)bb * NN + n0 + row) * CCH + c0 + q + k * 4);
        *(float4*)&T[row][q + k * 4] = v;
    }
    __syncthreads();
    f16x8 o0, o1;
#pragma unroll
    for (int j = 0; j < 8; ++j) o0[j] = (_Float16)T[q + j][row];
#pragma unroll
    for (int j = 0; j < 8; ++j) o1[j] = (_Float16)T[q + 8 + j][row];
    _Float16* dst = Vt + ((size_t)bb * CCH + c0 + row) * NN + n0 + q;
    *(f16x8*)dst = o0;
    *(f16x8*)(dst + 8) = o1;
}

// ---------------------------------------------------------------------------
// MFMA flash attention v6: 512 threads / 8 waves per block, 16 q-rows per
// wave (same 128-q block, grid 256).  2 waves/SIMD so one wave's MFMA stream
// hides the other's LDS/softmax latency.  S^T formulation, 128-kv rounds,
// K-chunk/V register-prefetch pipelining, XOR-swizzled LDS.  Dynamic LDS
// 130 KB, 1 block/CU, grid 256, batch = blockIdx&7 pins batch -> XCD.
// ---------------------------------------------------------------------------
__global__ __launch_bounds__(512, 2)
void attn_mfma_kernel(const __bf16* __restrict__ Qhi, const __bf16* __restrict__ Qlo,
                      const __bf16* __restrict__ Khi, const __bf16* __restrict__ Klo,
                      const _Float16* __restrict__ Vt, const float* __restrict__ alpha_p,
                      float* __restrict__ out) {
    const int bb = blockIdx.x & 7;     // batch -> XCD
    const int qb = blockIdx.x >> 3;    // 0..31
    const int n0 = qb * 128;
    const int tid  = threadIdx.x;
    const int wave = tid >> 6;         // 0..7
    const int lane = tid & 63;
    const int quad = lane >> 4;
    const int l16  = lane & 15;
    const int xq   = l16 & 7;

    extern __shared__ __align__(16) unsigned char smem[];
    __bf16*   KsHi = (__bf16*)(smem);                 // [128][64] swizzled
    __bf16*   KsLo = (__bf16*)(smem + 16384);         // [128][64] swizzled
    _Float16* Vs   = (_Float16*)(smem + 32768);       // [256][128] swizzled
    _Float16* Pw   = (_Float16*)(smem + 98304) + wave * 16 * 136;  // [16][136]

    // Q resident in registers as B-frags: this wave's 16 q-rows
    bf16x8 qh[8], ql[8];
    {
        const size_t base = ((size_t)bb * NN + n0 + wave * 16 + l16) * CCH + quad * 8;
#pragma unroll
        for (int ks = 0; ks < 8; ++ks) {
            qh[ks] = *(const bf16x8*)(Qhi + base + ks * 32);
            ql[ks] = *(const bf16x8*)(Qlo + base + ks * 32);
        }
    }

    f32x4 Oacc[16];    // [cf]: O^T c=cf*16+quad*4+r, q=l16
#pragma unroll
    for (int cf = 0; cf < 16; ++cf) Oacc[cf] = (f32x4){0.f, 0.f, 0.f, 0.f};
    float m_i = -INFINITY, l_i = 0.f;

    // staging coords: K: 4 thr/row (128 rows), 2x16B units each per hi/lo
    const int krow = tid >> 2, kq4 = tid & 3;
    // V: 2 thr/row (256 rows), 4x16B units per group
    const int vrow = tid >> 1, vh = tid & 1;

    bf16x8 kph[2], kpl[2];     // K-chunk prefetch regs
    f16x8  vp[4];              // V half prefetch regs

    auto kload = [&](int m0_, int cc_) {
#pragma unroll
        for (int i = 0; i < 2; ++i) {
            const int u = kq4 * 2 + i;
            const size_t g = ((size_t)bb * NN + m0_ + krow) * CCH + cc_ * 64 + u * 8;
            kph[i] = *(const bf16x8*)(Khi + g);
            kpl[i] = *(const bf16x8*)(Klo + g);
        }
    };
    auto kwrite = [&]() {
#pragma unroll
        for (int i = 0; i < 2; ++i) {
            const int u = kq4 * 2 + i;
            const int lo = krow * 64 + ((u ^ (krow & 7)) * 8);
            *(bf16x8*)&KsHi[lo] = kph[i];
            *(bf16x8*)&KsLo[lo] = kpl[i];
        }
    };
    auto vload = [&](int m0_, int grp) {
#pragma unroll
        for (int i = 0; i < 4; ++i) {
            const int u = grp * 8 + vh * 4 + i;
            vp[i] = *(const f16x8*)(Vt + ((size_t)bb * CCH + vrow) * NN + m0_ + u * 8);
        }
    };
    auto vwrite = [&](int grp) {
#pragma unroll
        for (int i = 0; i < 4; ++i) {
            const int u = grp * 8 + vh * 4 + i;
            *(f16x8*)&Vs[vrow * 128 + ((u ^ (vrow & 7)) * 8)] = vp[i];
        }
    };

    f32x4 Sacc[8];
    auto schunk = [&](int cc) {
#pragma unroll
        for (int ks = 0; ks < 2; ++ks) {
            const int kq = cc * 2 + ks;
#pragma unroll
            for (int kvt = 0; kvt < 8; ++kvt) {
                const int off = (kvt * 16 + l16) * 64 + (((ks * 4 + quad) ^ xq) * 8);
                const bf16x8 kh = *(const bf16x8*)&KsHi[off];
                const bf16x8 kl = *(const bf16x8*)&KsLo[off];
                Sacc[kvt] = __builtin_amdgcn_mfma_f32_16x16x32_bf16(kh, qh[kq], Sacc[kvt], 0, 0, 0);
                Sacc[kvt] = __builtin_amdgcn_mfma_f32_16x16x32_bf16(kl, qh[kq], Sacc[kvt], 0, 0, 0);
                Sacc[kvt] = __builtin_amdgcn_mfma_f32_16x16x32_bf16(kh, ql[kq], Sacc[kvt], 0, 0, 0);
            }
        }
    };

    // prologue: stage K chunk0 of tile 0
    kload(0, 0);
    kwrite();
    __syncthreads();

    for (int t = 0; t < 32; ++t) {
        const int m0 = t * 128;
#pragma unroll
        for (int kvt = 0; kvt < 8; ++kvt) Sacc[kvt] = (f32x4){0.f, 0.f, 0.f, 0.f};

        // ---- S chunks 0..2 with chunk c+1 prefetch ----
        for (int cc = 0; cc < 3; ++cc) {
            kload(m0, cc + 1);
            schunk(cc);
            __syncthreads();          // all waves done reading chunk cc
            kwrite();
            __syncthreads();          // chunk cc+1 visible
        }

        // ---- S chunk 3; V prefetched in two halves ----
        vload(m0, 0);
        schunk(3);
        vwrite(0);                    // V region safe: last read before tile start
        vload(m0, 1);

        // ---- online softmax over 128 kv ----
        float mx = -INFINITY;
#pragma unroll
        for (int kvt = 0; kvt < 8; ++kvt)
#pragma unroll
            for (int r = 0; r < 4; ++r) mx = fmaxf(mx, Sacc[kvt][r]);
        mx = fmaxf(mx, __shfl_xor(mx, 16, 64));
        mx = fmaxf(mx, __shfl_xor(mx, 32, 64));
        const float mnew = fmaxf(m_i, mx);
        float rs = 0.f;
#pragma unroll
        for (int kvt = 0; kvt < 8; ++kvt) {
            f16x4 pw;
#pragma unroll
            for (int r = 0; r < 4; ++r) {
                const float p = __expf(Sacc[kvt][r] - mnew);
                rs += p;
                pw[r] = (_Float16)p;
            }
            *(f16x4*)&Pw[l16 * 136 + kvt * 16 + quad * 4] = pw;
        }
        rs += __shfl_xor(rs, 16, 64);
        rs += __shfl_xor(rs, 32, 64);
        const float scale = __expf(m_i - mnew);    // 0 on first tile
        l_i = l_i * scale + rs;
        m_i = mnew;
#pragma unroll
        for (int cf = 0; cf < 16; ++cf) {
            Oacc[cf][0] *= scale;
            Oacc[cf][1] *= scale;
            Oacc[cf][2] *= scale;
            Oacc[cf][3] *= scale;
        }
        vwrite(1);
        __syncthreads();              // V visible; all waves past chunk3 reads

        // ---- O^T += V^T P^T; prefetch next tile's K chunk0 ----
        kload((t == 31) ? 0 : m0 + 128, 0);
        f16x8 pf[4];
#pragma unroll
        for (int kvf = 0; kvf < 4; ++kvf)
            pf[kvf] = *(const f16x8*)&Pw[l16 * 136 + kvf * 32 + quad * 8];
#pragma unroll
        for (int cf = 0; cf < 16; ++cf) {
#pragma unroll
            for (int kvf = 0; kvf < 4; ++kvf) {
                const f16x8 vf = *(const f16x8*)&Vs[(cf * 16 + l16) * 128 + (((kvf * 4 + quad) ^ xq) * 8)];
                Oacc[cf] = __builtin_amdgcn_mfma_f32_16x16x32_f16(vf, pf[kvf], Oacc[cf], 0, 0, 0);
            }
        }
        kwrite();                     // K buffer safe: chunk3 reads ended pre-barrier
        __syncthreads();              // chunk0(t+1) visible; V reads done
    }

    // ---- epilogue: /l, *alpha, write out[b][c][n] ----
    const float alpha = *alpha_p;
    const float inv = alpha / l_i;
    const int qg = n0 + wave * 16 + l16;
#pragma unroll
    for (int cf = 0; cf < 16; ++cf) {
#pragma unroll
        for (int r = 0; r < 4; ++r) {
            const int c = cf * 16 + quad * 4 + r;
            out[((size_t)bb * CCH + c) * NN + qg] = Oacc[cf][r] * inv;
        }
    }
}

// ---------------------------------------------------------------------------
extern "C" void kernel_launch(void* const* d_in, const int* in_sizes, int n_in,
                              void* d_out, int out_size, void* d_ws, size_t ws_size,
                              hipStream_t stream) {
    const float* X  = (const float*)d_in[0];
    const float* w1 = (const float*)d_in[1];
    const float* b1 = (const float*)d_in[2];
    const float* w2 = (const float*)d_in[3];
    const float* b2 = (const float*)d_in[4];
    const float* w3 = (const float*)d_in[5];
    const float* b3 = (const float*)d_in[6];
    const float* alpha = (const float*)d_in[7];
    float* out = (float*)d_out;

    float*    Dws = (float*)d_ws;
    __bf16*   Qhi = (__bf16*)(Dws + (size_t)BNC);
    __bf16*   Qlo = Qhi + (size_t)BNC;
    __bf16*   Khi = Qlo + (size_t)BNC;
    __bf16*   Klo = Khi + (size_t)BNC;
    _Float16* Vt  = (_Float16*)(Klo + (size_t)BNC);
    _Float16* Xhi = Vt + (size_t)BNC;
    _Float16* Xlo = Xhi + (size_t)BNC;
    _Float16* Whi = Xlo + (size_t)BNC;
    _Float16* Wlo = Whi + (size_t)WELEMS;

    wtrans_kernel<<<dim3(WELEMS / 256), 256, 0, stream>>>(w1, w2, w3, Whi, Wlo);

    xsplit_kernel<<<dim3(HH, CCH / 64, BATCH), 256, 0, stream>>>(X, Xhi, Xlo);

    conv_mfma_kernel<<<dim3(HH, BATCH, 3), 512, 0, stream>>>(
        Xhi, Xlo, Whi, Wlo, b1, b2, b3, Qhi, Qlo, Khi, Klo, Dws);

    transpose_v_kernel<<<dim3(NN / 64, CCH / 64, BATCH), 256, 0, stream>>>(Dws, Vt);

    // dynamic LDS: K chunk hi/lo 32 KB + V 64 KB + P 34 KB = 133120 B
    attn_mfma_kernel<<<dim3(256), 512, 133120, stream>>>(
        Qhi, Qlo, Khi, Klo, Vt, alpha, out);
}

// Round 6
// 586.207 us; speedup vs baseline: 1.5938x; 1.0261x over previous
//
#include <hip/hip_runtime.h>
#include <math.h>

#define BATCH 8
#define CCH   256
#define HH    64
#define WW    64
#define NN    4096                    // HH*WW

#define BNC   (BATCH * NN * CCH)      // 8,388,608 elems per tensor
#define WELEMS (3 * 8 * 9 * 256 * 32) // 1,769,472 fp16 weight elems per hi/lo

typedef __bf16   bf16x8 __attribute__((ext_vector_type(8)));
typedef _Float16 f16x8  __attribute__((ext_vector_type(8)));
typedef _Float16 f16x4  __attribute__((ext_vector_type(4)));
typedef float    f32x4  __attribute__((ext_vector_type(4)));

// ---------------------------------------------------------------------------
// Weights: OIHW fp32 -> fp16 hi/lo, layout [conv][cc8][tap9][co256][ci32]
// ---------------------------------------------------------------------------
__global__ void wtrans_kernel(const float* __restrict__ w1,
                              const float* __restrict__ w2,
                              const float* __restrict__ w3,
                              _Float16* __restrict__ Whi,
                              _Float16* __restrict__ Wlo) {
    int e = blockIdx.x * 256 + threadIdx.x;      // 0 .. WELEMS-1
    int t = e;
    const int ci  = t & 31;  t >>= 5;
    const int co  = t & 255; t >>= 8;
    const int tap = t % 9;   t /= 9;
    const int cc  = t & 7;   t >>= 3;
    const int conv = t;
    const float* src = (conv == 0) ? w1 : (conv == 1) ? w2 : w3;
    const float v = src[co * 2304 + (cc * 32 + ci) * 9 + tap];
    const _Float16 h = (_Float16)v;
    Whi[e] = h;
    Wlo[e] = (_Float16)(v - (float)h);
}

// ---------------------------------------------------------------------------
// X: [b][ci][h][w] fp32 -> Xhi/Xlo fp16 [b][h][w][ci]  (transpose via LDS)
// ---------------------------------------------------------------------------
__global__ __launch_bounds__(256)
void xsplit_kernel(const float* __restrict__ X,
                   _Float16* __restrict__ Xhi, _Float16* __restrict__ Xlo) {
    __shared__ float T[64][65];
    const int h = blockIdx.x, c0 = blockIdx.y * 64, bb = blockIdx.z;
    const int t = threadIdx.x;
    const int row = t >> 2, q = (t & 3) * 16;
#pragma unroll
    for (int k = 0; k < 4; ++k) {
        float4 v = *(const float4*)&X[(((size_t)bb * CCH + c0 + row) * HH + h) * WW + q + k * 4];
        *(float4*)&T[row][q + k * 4] = v;
    }
    __syncthreads();
    f16x8 h0, h1, l0, l1;
#pragma unroll
    for (int j = 0; j < 8; ++j) {
        float v = T[q + j][row];
        _Float16 hh = (_Float16)v;
        h0[j] = hh; l0[j] = (_Float16)(v - (float)hh);
    }
#pragma unroll
    for (int j = 0; j < 8; ++j) {
        float v = T[q + 8 + j][row];
        _Float16 hh = (_Float16)v;
        h1[j] = hh; l1[j] = (_Float16)(v - (float)hh);
    }
    const size_t g = (((size_t)bb * HH + h) * WW + row) * CCH + c0 + q;
    *(f16x8*)(Xhi + g) = h0;  *(f16x8*)(Xhi + g + 8) = h1;
    *(f16x8*)(Xlo + g) = l0;  *(f16x8*)(Xlo + g + 8) = l1;
}

// ---------------------------------------------------------------------------
// MFMA implicit-GEMM conv 3x3 SAME + bias, v6:
//  v4 geometry (2-row block, acc 4x4, 768 blocks, (512,2) spill-free) +
//  FULL-TAP W double-buffer: at tap t issue all 8 global loads (4 j x hi/lo)
//  for tap t+1; MFMA consumes the buffer filled one tap earlier.  Prefetch
//  distance 48 MFMA (~233 CU-cyc) >= L2 latency (~200 cyc) -- removes the
//  per-j-step W stall that pinned conv at ~355us across v2/v4/v5 (depth-1
//  prefetch = 58 cyc cover).  Buffer parity (cc+tap)&1 made compile-time by
//  unrolling cc in pairs (rule: runtime-indexed reg arrays spill).
//  Linear step st=cc*9+tap rolls across cc; last step wraps to 0 (harmless).
// ---------------------------------------------------------------------------
__global__ __launch_bounds__(512, 2)
void conv_mfma_kernel(const _Float16* __restrict__ Xhi, const _Float16* __restrict__ Xlo,
                      const _Float16* __restrict__ Whi, const _Float16* __restrict__ Wlo,
                      const float* __restrict__ b1, const float* __restrict__ b2,
                      const float* __restrict__ b3,
                      __bf16* __restrict__ Qhi, __bf16* __restrict__ Qlo,
                      __bf16* __restrict__ Khi, __bf16* __restrict__ Klo,
                      float* __restrict__ Dws) {
    const int h0   = blockIdx.x * 2;
    const int bb   = blockIdx.y;
    const int conv = blockIdx.z;
    const int tid  = threadIdx.x;
    const int wave = tid >> 6;
    const int lane = tid & 63;
    const int quad = lane >> 4;
    const int l16  = lane & 15;
    const int mg   = wave >> 2;
    const int ng   = wave & 3;

    // [4 rows][66 cols][32 ch], col 0 and 65 are zero pads
    __shared__ _Float16 XsH[4 * 66 * 32];
    __shared__ _Float16 XsL[4 * 66 * 32];

    const bool threePass = (conv < 2);
    const float* bias = (conv == 0) ? b1 : (conv == 1) ? b2 : b3;

    f32x4 acc[4][4];
#pragma unroll
    for (int j = 0; j < 4; ++j) {
        const float bv = bias[ng * 64 + j * 16 + l16];
#pragma unroll
        for (int i = 0; i < 4; ++i) acc[i][j] = (f32x4){bv, bv, bv, bv};
    }

    const f16x8 zf = {0, 0, 0, 0, 0, 0, 0, 0};
    const int xrow = tid >> 7;
    const int xw   = (tid >> 1) & 63;
    const int xch  = (tid & 1) * 16;
    const int xc0  = (tid & 1) * 2;       // first 16B-chunk index (0 or 2)

    // zero the pad columns once (cols 0 and 65, all 4 rows, all 32 ch)
    if (tid < 256) {
        const int zr = tid >> 6, zc = ((tid >> 5) & 1) ? 65 : 0, zch = tid & 31;
        XsH[(zr * 66 + zc) * 32 + zch] = (_Float16)0;
        XsL[(zr * 66 + zc) * 32 + zch] = (_Float16)0;
    }

    // per-lane LDS read bases for dw = 0,1,2 (col = i*16 + l16 + dw)
    int xb[3];
#pragma unroll
    for (int dw = 0; dw < 3; ++dw)
        xb[dw] = mg * 2112 + (l16 + dw) * 32 + ((quad ^ ((l16 + dw) & 3)) * 8);

    // W direct-from-global: per-lane offset inside a tap block [co256][ci32]
    const int wloff = (ng * 64 + l16) * 32 + quad * 8;
    const _Float16* WhB = Whi + (size_t)conv * 589824;
    const _Float16* WlB = Wlo + (size_t)conv * 589824;

    // W tap double-buffers: wbh/wbl[parity][j]
    f16x8 wbh[2][4], wbl[2][4];
#pragma unroll
    for (int j = 0; j < 4; ++j) {
        wbh[0][j] = *(const f16x8*)(WhB + wloff + j * 512);
        wbl[0][j] = zf;
        if (threePass) wbl[0][j] = *(const f16x8*)(WlB + wloff + j * 512);
    }

    for (int cc2 = 0; cc2 < 4; ++cc2) {
#pragma unroll
        for (int ccp = 0; ccp < 2; ++ccp) {
            const int cc = cc2 * 2 + ccp;
            __syncthreads();                  // previous cc's LDS reads done
            {
                const int h = h0 - 1 + xrow;
                f16x8 a0 = zf, a1 = zf, b0 = zf, b1v = zf;
                if ((unsigned)h < (unsigned)HH) {
                    const size_t g = (((size_t)bb * HH + h) * WW + xw) * CCH + cc * 32 + xch;
                    a0 = *(const f16x8*)(Xhi + g);  a1 = *(const f16x8*)(Xhi + g + 8);
                    if (threePass) { b0 = *(const f16x8*)(Xlo + g);  b1v = *(const f16x8*)(Xlo + g + 8); }
                }
                // write col xw+1 (data cols are 1..64), swizzle units by (col&3)
                const int col = xw + 1;
                const int lbase = (xrow * 66 + col) * 32;
                const int s3 = col & 3;
                *(f16x8*)&XsH[lbase + ((xc0 ^ s3) * 8)]       = a0;
                *(f16x8*)&XsH[lbase + (((xc0 + 1) ^ s3) * 8)] = a1;
                if (threePass) {
                    *(f16x8*)&XsL[lbase + ((xc0 ^ s3) * 8)]       = b0;
                    *(f16x8*)&XsL[lbase + (((xc0 + 1) ^ s3) * 8)] = b1v;
                }
            }
            __syncthreads();                  // X tile visible

#pragma unroll
            for (int tap = 0; tap < 9; ++tap) {
                const int p  = (ccp + tap) & 1;   // compile-time parity
                const int np = p ^ 1;
                // ---- prefetch next tap's W fragments into ping buffer ----
                {
                    const int nst = cc * 9 + tap + 1;          // 1..72
                    const size_t nb = (size_t)(nst == 72 ? 0 : nst) * 8192 + wloff;
#pragma unroll
                    for (int j = 0; j < 4; ++j) {
                        wbh[np][j] = *(const f16x8*)(WhB + nb + j * 512);
                        if (threePass) wbl[np][j] = *(const f16x8*)(WlB + nb + j * 512);
                    }
                }
                // ---- LDS A fragments ----
                const int dh = tap / 3, dw = tap % 3;          // compile-time
                f16x8 ah[4], al[4];
#pragma unroll
                for (int i = 0; i < 4; ++i) {
                    const int off = xb[dw] + dh * 2112 + i * 512;  // imm-folded
                    ah[i] = *(const f16x8*)&XsH[off];
                    if (threePass) al[i] = *(const f16x8*)&XsL[off];
                }
                // ---- MFMA with pong buffer (filled one full tap ago) ----
#pragma unroll
                for (int j = 0; j < 4; ++j) {
                    if (threePass) {
#pragma unroll
                        for (int i = 0; i < 4; ++i) {
                            acc[i][j] = __builtin_amdgcn_mfma_f32_16x16x32_f16(ah[i], wbh[p][j], acc[i][j], 0, 0, 0);
                            acc[i][j] = __builtin_amdgcn_mfma_f32_16x16x32_f16(al[i], wbh[p][j], acc[i][j], 0, 0, 0);
                            acc[i][j] = __builtin_amdgcn_mfma_f32_16x16x32_f16(ah[i], wbl[p][j], acc[i][j], 0, 0, 0);
                        }
                    } else {
#pragma unroll
                        for (int i = 0; i < 4; ++i)
                            acc[i][j] = __builtin_amdgcn_mfma_f32_16x16x32_f16(ah[i], wbh[p][j], acc[i][j], 0, 0, 0);
                    }
                }
            }
        }
    }

    const size_t nb = (size_t)bb * NN + (size_t)(h0 + mg) * 64;
    if (threePass) {
        __bf16* Hi = conv ? Khi : Qhi;
        __bf16* Lo = conv ? Klo : Qlo;
#pragma unroll
        for (int i = 0; i < 4; ++i) {
            const int wx0 = i * 16 + quad * 4;
#pragma unroll
            for (int j = 0; j < 4; ++j) {
                const int co = ng * 64 + j * 16 + l16;
#pragma unroll
                for (int r = 0; r < 4; ++r) {
                    const float v = acc[i][j][r];
                    const size_t idx = (nb + wx0 + r) * CCH + co;
                    const __bf16 hq = (__bf16)v;
                    Hi[idx] = hq;
                    Lo[idx] = (__bf16)(v - (float)hq);
                }
            }
        }
    } else {
#pragma unroll
        for (int i = 0; i < 4; ++i) {
            const int wx0 = i * 16 + quad * 4;
#pragma unroll
            for (int j = 0; j < 4; ++j) {
                const int co = ng * 64 + j * 16 + l16;
#pragma unroll
                for (int r = 0; r < 4; ++r)
                    Dws[(nb + wx0 + r) * CCH + co] = acc[i][j][r];
            }
        }
    }
}

// ---------------------------------------------------------------------------
// Transpose D (fp32 [b][n][c]) -> Vt (fp16 [b][c][n]).
// ---------------------------------------------------------------------------
__global__ __launch_bounds__(256)
void transpose_v_kernel(const float* __restrict__ D, _Float16* __restrict__ Vt) {
    __shared__ float T[64][65];
    const int n0 = blockIdx.x * 64, c0 = blockIdx.y * 64, bb = blockIdx.z;
    const int t = threadIdx.x;
    const int row = t >> 2, q = (t & 3) * 16;
#pragma unroll
    for (int k = 0; k < 4; ++k) {
        float4 v = *(const float4*)(D + ((size_t)bb * NN + n0 + row) * CCH + c0 + q + k * 4);
        *(float4*)&T[row][q + k * 4] = v;
    }
    __syncthreads();
    f16x8 o0, o1;
#pragma unroll
    for (int j = 0; j < 8; ++j) o0[j] = (_Float16)T[q + j][row];
#pragma unroll
    for (int j = 0; j < 8; ++j) o1[j] = (_Float16)T[q + 8 + j][row];
    _Float16* dst = Vt + ((size_t)bb * CCH + c0 + row) * NN + n0 + q;
    *(f16x8*)dst = o0;
    *(f16x8*)(dst + 8) = o1;
}

// ---------------------------------------------------------------------------
// MFMA flash attention v6: 512 threads / 8 waves per block, 16 q-rows per
// wave (same 128-q block, grid 256).  2 waves/SIMD so one wave's MFMA stream
// hides the other's LDS/softmax latency.  S^T formulation, 128-kv rounds,
// K-chunk/V register-prefetch pipelining, XOR-swizzled LDS.  Dynamic LDS
// 130 KB, 1 block/CU, grid 256, batch = blockIdx&7 pins batch -> XCD.
// ---------------------------------------------------------------------------
__global__ __launch_bounds__(512, 2)
void attn_mfma_kernel(const __bf16* __restrict__ Qhi, const __bf16* __restrict__ Qlo,
                      const __bf16* __restrict__ Khi, const __bf16* __restrict__ Klo,
                      const _Float16* __restrict__ Vt, const float* __restrict__ alpha_p,
                      float* __restrict__ out) {
    const int bb = blockIdx.x & 7;     // batch -> XCD
    const int qb = blockIdx.x >> 3;    // 0..31
    const int n0 = qb * 128;
    const int tid  = threadIdx.x;
    const int wave = tid >> 6;         // 0..7
    const int lane = tid & 63;
    const int quad = lane >> 4;
    const int l16  = lane & 15;
    const int xq   = l16 & 7;

    extern __shared__ __align__(16) unsigned char smem[];
    __bf16*   KsHi = (__bf16*)(smem);                 // [128][64] swizzled
    __bf16*   KsLo = (__bf16*)(smem + 16384);         // [128][64] swizzled
    _Float16* Vs   = (_Float16*)(smem + 32768);       // [256][128] swizzled
    _Float16* Pw   = (_Float16*)(smem + 98304) + wave * 16 * 136;  // [16][136]

    // Q resident in registers as B-frags: this wave's 16 q-rows
    bf16x8 qh[8], ql[8];
    {
        const size_t base = ((size_t)bb * NN + n0 + wave * 16 + l16) * CCH + quad * 8;
#pragma unroll
        for (int ks = 0; ks < 8; ++ks) {
            qh[ks] = *(const bf16x8*)(Qhi + base + ks * 32);
            ql[ks] = *(const bf16x8*)(Qlo + base + ks * 32);
        }
    }

    f32x4 Oacc[16];    // [cf]: O^T c=cf*16+quad*4+r, q=l16
#pragma unroll
    for (int cf = 0; cf < 16; ++cf) Oacc[cf] = (f32x4){0.f, 0.f, 0.f, 0.f};
    float m_i = -INFINITY, l_i = 0.f;

    // staging coords: K: 4 thr/row (128 rows), 2x16B units each per hi/lo
    const int krow = tid >> 2, kq4 = tid & 3;
    // V: 2 thr/row (256 rows), 4x16B units per group
    const int vrow = tid >> 1, vh = tid & 1;

    bf16x8 kph[2], kpl[2];     // K-chunk prefetch regs
    f16x8  vp[4];              // V half prefetch regs

    auto kload = [&](int m0_, int cc_) {
#pragma unroll
        for (int i = 0; i < 2; ++i) {
            const int u = kq4 * 2 + i;
            const size_t g = ((size_t)bb * NN + m0_ + krow) * CCH + cc_ * 64 + u * 8;
            kph[i] = *(const bf16x8*)(Khi + g);
            kpl[i] = *(const bf16x8*)(Klo + g);
        }
    };
    auto kwrite = [&]() {
#pragma unroll
        for (int i = 0; i < 2; ++i) {
            const int u = kq4 * 2 + i;
            const int lo = krow * 64 + ((u ^ (krow & 7)) * 8);
            *(bf16x8*)&KsHi[lo] = kph[i];
            *(bf16x8*)&KsLo[lo] = kpl[i];
        }
    };
    auto vload = [&](int m0_, int grp) {
#pragma unroll
        for (int i = 0; i < 4; ++i) {
            const int u = grp * 8 + vh * 4 + i;
            vp[i] = *(const f16x8*)(Vt + ((size_t)bb * CCH + vrow) * NN + m0_ + u * 8);
        }
    };
    auto vwrite = [&](int grp) {
#pragma unroll
        for (int i = 0; i < 4; ++i) {
            const int u = grp * 8 + vh * 4 + i;
            *(f16x8*)&Vs[vrow * 128 + ((u ^ (vrow & 7)) * 8)] = vp[i];
        }
    };

    f32x4 Sacc[8];
    auto schunk = [&](int cc) {
#pragma unroll
        for (int ks = 0; ks < 2; ++ks) {
            const int kq = cc * 2 + ks;
#pragma unroll
            for (int kvt = 0; kvt < 8; ++kvt) {
                const int off = (kvt * 16 + l16) * 64 + (((ks * 4 + quad) ^ xq) * 8);
                const bf16x8 kh = *(const bf16x8*)&KsHi[off];
                const bf16x8 kl = *(const bf16x8*)&KsLo[off];
                Sacc[kvt] = __builtin_amdgcn_mfma_f32_16x16x32_bf16(kh, qh[kq], Sacc[kvt], 0, 0, 0);
                Sacc[kvt] = __builtin_amdgcn_mfma_f32_16x16x32_bf16(kl, qh[kq], Sacc[kvt], 0, 0, 0);
                Sacc[kvt] = __builtin_amdgcn_mfma_f32_16x16x32_bf16(kh, ql[kq], Sacc[kvt], 0, 0, 0);
            }
        }
    };

    // prologue: stage K chunk0 of tile 0
    kload(0, 0);
    kwrite();
    __syncthreads();

    for (int t = 0; t < 32; ++t) {
        const int m0 = t * 128;
#pragma unroll
        for (int kvt = 0; kvt < 8; ++kvt) Sacc[kvt] = (f32x4){0.f, 0.f, 0.f, 0.f};

        // ---- S chunks 0..2 with chunk c+1 prefetch ----
        for (int cc = 0; cc < 3; ++cc) {
            kload(m0, cc + 1);
            schunk(cc);
            __syncthreads();          // all waves done reading chunk cc
            kwrite();
            __syncthreads();          // chunk cc+1 visible
        }

        // ---- S chunk 3; V prefetched in two halves ----
        vload(m0, 0);
        schunk(3);
        vwrite(0);                    // V region safe: last read before tile start
        vload(m0, 1);

        // ---- online softmax over 128 kv ----
        float mx = -INFINITY;
#pragma unroll
        for (int kvt = 0; kvt < 8; ++kvt)
#pragma unroll
            for (int r = 0; r < 4; ++r) mx = fmaxf(mx, Sacc[kvt][r]);
        mx = fmaxf(mx, __shfl_xor(mx, 16, 64));
        mx = fmaxf(mx, __shfl_xor(mx, 32, 64));
        const float mnew = fmaxf(m_i, mx);
        float rs = 0.f;
#pragma unroll
        for (int kvt = 0; kvt < 8; ++kvt) {
            f16x4 pw;
#pragma unroll
            for (int r = 0; r < 4; ++r) {
                const float p = __expf(Sacc[kvt][r] - mnew);
                rs += p;
                pw[r] = (_Float16)p;
            }
            *(f16x4*)&Pw[l16 * 136 + kvt * 16 + quad * 4] = pw;
        }
        rs += __shfl_xor(rs, 16, 64);
        rs += __shfl_xor(rs, 32, 64);
        const float scale = __expf(m_i - mnew);    // 0 on first tile
        l_i = l_i * scale + rs;
        m_i = mnew;
#pragma unroll
        for (int cf = 0; cf < 16; ++cf) {
            Oacc[cf][0] *= scale;
            Oacc[cf][1] *= scale;
            Oacc[cf][2] *= scale;
            Oacc[cf][3] *= scale;
        }
        vwrite(1);
        __syncthreads();              // V visible; all waves past chunk3 reads

        // ---- O^T += V^T P^T; prefetch next tile's K chunk0 ----
        kload((t == 31) ? 0 : m0 + 128, 0);
        f16x8 pf[4];
#pragma unroll
        for (int kvf = 0; kvf < 4; ++kvf)
            pf[kvf] = *(const f16x8*)&Pw[l16 * 136 + kvf * 32 + quad * 8];
#pragma unroll
        for (int cf = 0; cf < 16; ++cf) {
#pragma unroll
            for (int kvf = 0; kvf < 4; ++kvf) {
                const f16x8 vf = *(const f16x8*)&Vs[(cf * 16 + l16) * 128 + (((kvf * 4 + quad) ^ xq) * 8)];
                Oacc[cf] = __builtin_amdgcn_mfma_f32_16x16x32_f16(vf, pf[kvf], Oacc[cf], 0, 0, 0);
            }
        }
        kwrite();                     // K buffer safe: chunk3 reads ended pre-barrier
        __syncthreads();              // chunk0(t+1) visible; V reads done
    }

    // ---- epilogue: /l, *alpha, write out[b][c][n] ----
    const float alpha = *alpha_p;
    const float inv = alpha / l_i;
    const int qg = n0 + wave * 16 + l16;
#pragma unroll
    for (int cf = 0; cf < 16; ++cf) {
#pragma unroll
        for (int r = 0; r < 4; ++r) {
            const int c = cf * 16 + quad * 4 + r;
            out[((size_t)bb * CCH + c) * NN + qg] = Oacc[cf][r] * inv;
        }
    }
}

// ---------------------------------------------------------------------------
extern "C" void kernel_launch(void* const* d_in, const int* in_sizes, int n_in,
                              void* d_out, int out_size, void* d_ws, size_t ws_size,
                              hipStream_t stream) {
    const float* X  = (const float*)d_in[0];
    const float* w1 = (const float*)d_in[1];
    const float* b1 = (const float*)d_in[2];
    const float* w2 = (const float*)d_in[3];
    const float* b2 = (const float*)d_in[4];
    const float* w3 = (const float*)d_in[5];
    const float* b3 = (const float*)d_in[6];
    const float* alpha = (const float*)d_in[7];
    float* out = (float*)d_out;

    float*    Dws = (float*)d_ws;
    __bf16*   Qhi = (__bf16*)(Dws + (size_t)BNC);
    __bf16*   Qlo = Qhi + (size_t)BNC;
    __bf16*   Khi = Qlo + (size_t)BNC;
    __bf16*   Klo = Khi + (size_t)BNC;
    _Float16* Vt  = (_Float16*)(Klo + (size_t)BNC);
    _Float16* Xhi = Vt + (size_t)BNC;
    _Float16* Xlo = Xhi + (size_t)BNC;
    _Float16* Whi = Xlo + (size_t)BNC;
    _Float16* Wlo = Whi + (size_t)WELEMS;

    wtrans_kernel<<<dim3(WELEMS / 256), 256, 0, stream>>>(w1, w2, w3, Whi, Wlo);

    xsplit_kernel<<<dim3(HH, CCH / 64, BATCH), 256, 0, stream>>>(X, Xhi, Xlo);

    conv_mfma_kernel<<<dim3(HH / 2, BATCH, 3), 512, 0, stream>>>(
        Xhi, Xlo, Whi, Wlo, b1, b2, b3, Qhi, Qlo, Khi, Klo, Dws);

    transpose_v_kernel<<<dim3(NN / 64, CCH / 64, BATCH), 256, 0, stream>>>(Dws, Vt);

    // dynamic LDS: K chunk hi/lo 32 KB + V 64 KB + P 34 KB = 133120 B
    attn_mfma_kernel<<<dim3(256), 512, 133120, stream>>>(
        Qhi, Qlo, Khi, Klo, Vt, alpha, out);
}